// Round 4
// baseline (128.404 us; speedup 1.0000x reference)
//
#include <hip/hip_runtime.h>
#include <hip/hip_bf16.h>

#define D_DIM 768
#define K_CL  512
#define BM    128
#define BK    32
#define NSTEP 24          // 768 / 32

using f32x4 = __attribute__((ext_vector_type(4))) float;
using s16x8 = __attribute__((ext_vector_type(8))) short;
using u16x8 = __attribute__((ext_vector_type(8))) unsigned short;
using u16x4 = __attribute__((ext_vector_type(4))) unsigned short;
typedef unsigned int u32;

static __device__ __forceinline__ unsigned short f2bf(float f) {
    __hip_bfloat16 h = __float2bfloat16(f);   // RTN
    unsigned short u;
    __builtin_memcpy(&u, &h, 2);
    return u;
}

static __device__ __forceinline__ void gload_lds16(const void* g, void* l) {
    __builtin_amdgcn_global_load_lds(
        (const __attribute__((address_space(1))) u32*)g,
        (__attribute__((address_space(3))) u32*)l, 16, 0, 0);
}

// Prepass: C[512][768] fp32 -> bf16 workspace in "LDS image" layout:
// granule (16B = 8 bf16) index  g = t*2048 + r*4 + (s ^ ((r>>1)&3))
// holds C[r][t*32 + s*8 .. +8).  Also c_sq[512].
__global__ void prep_centers_kernel(const float* __restrict__ C,
                                    unsigned short* __restrict__ Cbws,
                                    float* __restrict__ csq) {
    const int r = blockIdx.x;          // 0..511
    const int l = threadIdx.x;         // 0..63
    const float* src = C + (size_t)r * D_DIM;
    float sq = 0.f;
#pragma unroll
    for (int jj = 0; jj < 2; ++jj) {
        const int j = l + jj * 64;     // 0..127, only 0..95 valid
        if (j < 96) {
            const int t = j >> 2, s = j & 3;
            const int k0 = t * 32 + s * 8;
            f32x4 v0 = *reinterpret_cast<const f32x4*>(src + k0);
            f32x4 v1 = *reinterpret_cast<const f32x4*>(src + k0 + 4);
            u16x8 b;
            b[0] = f2bf(v0[0]); b[1] = f2bf(v0[1]); b[2] = f2bf(v0[2]); b[3] = f2bf(v0[3]);
            b[4] = f2bf(v1[0]); b[5] = f2bf(v1[1]); b[6] = f2bf(v1[2]); b[7] = f2bf(v1[3]);
            sq += v0[0]*v0[0] + v0[1]*v0[1] + v0[2]*v0[2] + v0[3]*v0[3]
                + v1[0]*v1[0] + v1[1]*v1[1] + v1[2]*v1[2] + v1[3]*v1[3];
            const int g = t * 2048 + r * 4 + (s ^ ((r >> 1) & 3));
            *reinterpret_cast<u16x8*>(Cbws + (size_t)g * 8) = b;
        }
    }
#pragma unroll
    for (int m = 1; m < 64; m <<= 1) sq += __shfl_xor(sq, m, 64);
    if (l == 0) csq[r] = sq;
}

// Main: 128 rows x 512 clusters per block, 8 waves, wave tile 128x64 (1m x 8n).
// B via global_load_lds dbuf, counted vmcnt across raw barriers; A dbuf reg->LDS.
__global__ __launch_bounds__(512, 2) void dec_main_kernel(
    const float* __restrict__ X,
    const unsigned short* __restrict__ Cbws,
    const float* __restrict__ csq,
    const float* __restrict__ alpha_ptr,
    float* __restrict__ out)
{
    __shared__ unsigned short Al[2][BM * BK];      // 2 * 8 KB
    __shared__ unsigned short Bl[2][K_CL * BK];    // 2 * 32 KB
    __shared__ float part[8][BM];                  // 4 KB
    __shared__ float xsql[BM];
    __shared__ float invl[BM];

    const int tid  = threadIdx.x;      // 0..511
    const int lane = tid & 63;
    const int wn   = tid >> 6;         // 0..7 (wave owns 64-col cluster stripe)
    const int m0   = blockIdx.x * BM;

    // ---- A staging: 4 threads per row, 8 fp32 each ----
    const int arow = tid >> 2;                 // 0..127
    const int as4  = tid & 3;                  // 16B granule within 64B row
    const float* aptr = X + (size_t)(m0 + arow) * D_DIM + as4 * 8;
    const int awbyte = arow * 64 + ((as4 ^ ((arow >> 1) & 3)) << 4);

    // ---- fragment read offsets (XOR-swizzled, verified 0-conflict) ----
    const int fr = lane & 15;
    const int fg = lane >> 4;
    int aoff[8], boff[4];
#pragma unroll
    for (int mf = 0; mf < 8; ++mf) {
        const int r = mf * 16 + fr;
        aoff[mf] = r * 64 + ((fg ^ ((r >> 1) & 3)) << 4);
    }
#pragma unroll
    for (int nf = 0; nf < 4; ++nf) {
        const int r = wn * 64 + nf * 16 + fr;
        boff[nf] = r * 64 + ((fg ^ ((r >> 1) & 3)) << 4);
    }

    f32x4 acc[8][4] = {};
    float sqp = 0.f;

    // ---- prologue ----
    f32x4 a0 = *reinterpret_cast<const f32x4*>(aptr);          // tile 0
    f32x4 a1 = *reinterpret_cast<const f32x4*>(aptr + 4);
    {   // issue B(0) DMA AFTER a-loads (so compiler's a-wait leaves DMA in flight)
        const unsigned short* bs = Cbws + (size_t)tid * 8;
#pragma unroll
        for (int q = 0; q < 4; ++q)
            gload_lds16(bs + (size_t)q * 512 * 8,
                        (char*)&Bl[0][0] + ((size_t)q * 512 + tid) * 16);
    }
    {   // stage A(0)
        u16x8 aw;
        aw[0] = f2bf(a0[0]); aw[1] = f2bf(a0[1]); aw[2] = f2bf(a0[2]); aw[3] = f2bf(a0[3]);
        aw[4] = f2bf(a1[0]); aw[5] = f2bf(a1[1]); aw[6] = f2bf(a1[2]); aw[7] = f2bf(a1[3]);
        sqp += a0[0]*a0[0] + a0[1]*a0[1] + a0[2]*a0[2] + a0[3]*a0[3]
             + a1[0]*a1[0] + a1[1]*a1[1] + a1[2]*a1[2] + a1[3]*a1[3];
        *reinterpret_cast<u16x8*>((char*)&Al[0][0] + awbyte) = aw;
    }
    a0 = *reinterpret_cast<const f32x4*>(aptr + BK);           // tile 1
    a1 = *reinterpret_cast<const f32x4*>(aptr + BK + 4);
    asm volatile("s_waitcnt vmcnt(2) lgkmcnt(0)" ::: "memory"); // B(0) done, a(1) in flight
    __builtin_amdgcn_sched_barrier(0);
    __builtin_amdgcn_s_barrier();

    for (int t = 0; t < NSTEP; ++t) {
        const int buf = t & 1;
        // 1. issue B-DMA(t+1) -> buf^1 (prev barrier fenced all buf^1 readers)
        if (t + 1 < NSTEP) {
            const unsigned short* bs = Cbws + (size_t)(t + 1) * 2048 * 8 + (size_t)tid * 8;
#pragma unroll
            for (int q = 0; q < 4; ++q)
                gload_lds16(bs + (size_t)q * 512 * 8,
                            (char*)&Bl[buf ^ 1][0] + ((size_t)q * 512 + tid) * 16);
        }
        // 2. compute(t): 8 A-frags, 4 B-frags, 32 MFMA
        {
            s16x8 afr[8];
#pragma unroll
            for (int mf = 0; mf < 8; ++mf)
                afr[mf] = *reinterpret_cast<const s16x8*>((const char*)&Al[buf][0] + aoff[mf]);
            __builtin_amdgcn_s_setprio(1);
#pragma unroll
            for (int nf = 0; nf < 4; ++nf) {
                s16x8 bfr = *reinterpret_cast<const s16x8*>((const char*)&Bl[buf][0] + boff[nf]);
#pragma unroll
                for (int mf = 0; mf < 8; ++mf)
                    acc[mf][nf] = __builtin_amdgcn_mfma_f32_16x16x32_bf16(
                        afr[mf], bfr, acc[mf][nf], 0, 0, 0);
            }
            __builtin_amdgcn_s_setprio(0);
        }
        // 3. stage A(t+1), prefetch a(t+2), counted wait + barrier
        if (t + 1 < NSTEP) {
            u16x8 aw;
            aw[0] = f2bf(a0[0]); aw[1] = f2bf(a0[1]); aw[2] = f2bf(a0[2]); aw[3] = f2bf(a0[3]);
            aw[4] = f2bf(a1[0]); aw[5] = f2bf(a1[1]); aw[6] = f2bf(a1[2]); aw[7] = f2bf(a1[3]);
            sqp += a0[0]*a0[0] + a0[1]*a0[1] + a0[2]*a0[2] + a0[3]*a0[3]
                 + a1[0]*a1[0] + a1[1]*a1[1] + a1[2]*a1[2] + a1[3]*a1[3];
            *reinterpret_cast<u16x8*>((char*)&Al[buf ^ 1][0] + awbyte) = aw;
            if (t + 2 < NSTEP) {
                a0 = *reinterpret_cast<const f32x4*>(aptr + (t + 2) * BK);
                a1 = *reinterpret_cast<const f32x4*>(aptr + (t + 2) * BK + 4);
                asm volatile("s_waitcnt vmcnt(2) lgkmcnt(0)" ::: "memory"); // B(t+1) done
            } else {
                asm volatile("s_waitcnt vmcnt(0) lgkmcnt(0)" ::: "memory");
            }
            __builtin_amdgcn_sched_barrier(0);
            __builtin_amdgcn_s_barrier();
        }
    }

    // ---- ||x||^2 per row: reduce 4 staging threads ----
    sqp += __shfl_xor(sqp, 1, 64);
    sqp += __shfl_xor(sqp, 2, 64);
    if ((tid & 3) == 0) xsql[arow] = sqp;
    __syncthreads();

    const float alpha     = alpha_ptr[0];
    const float inv_alpha = 1.0f / alpha;
    const float power     = 0.5f * (alpha + 1.0f);
    const bool  p1        = (power == 1.0f);

    float csqr[4];
#pragma unroll
    for (int nf = 0; nf < 4; ++nf)
        csqr[nf] = csq[wn * 64 + nf * 16 + fr];

    // numerator + per-row partial sums (16-lane butterfly in col group)
#pragma unroll
    for (int mf = 0; mf < 8; ++mf) {
#pragma unroll
        for (int j = 0; j < 4; ++j) {
            const int rloc = mf * 16 + fg * 4 + j;
            const float xs = xsql[rloc];
            float rp = 0.f;
#pragma unroll
            for (int nf = 0; nf < 4; ++nf) {
                float d2 = xs + csqr[nf] - 2.0f * acc[mf][nf][j];
                d2 = fmaxf(d2, 0.0f);
                const float base = 1.0f + d2 * inv_alpha;
                const float nm = p1 ? (1.0f / base)
                                    : exp2f(-power * log2f(base));
                acc[mf][nf][j] = nm;
                rp += nm;
            }
#pragma unroll
            for (int m = 1; m < 16; m <<= 1) rp += __shfl_xor(rp, m, 64);
            if (fr == 0) part[wn][rloc] = rp;
        }
    }
    __syncthreads();
    if (tid < BM) {
        float s = 0.f;
#pragma unroll
        for (int w = 0; w < 8; ++w) s += part[w][tid];
        invl[tid] = 1.0f / s;
    }
    __syncthreads();

    // scaled store (16 consecutive lanes -> 64B contiguous segments)
#pragma unroll
    for (int mf = 0; mf < 8; ++mf) {
#pragma unroll
        for (int j = 0; j < 4; ++j) {
            const int rloc = mf * 16 + fg * 4 + j;
            const float iv = invl[rloc];
            float* orow = out + (size_t)(m0 + rloc) * K_CL + wn * 64 + fr;
#pragma unroll
            for (int nf = 0; nf < 4; ++nf)
                orow[nf * 16] = acc[mf][nf][j] * iv;
        }
    }
}

extern "C" void kernel_launch(void* const* d_in, const int* in_sizes, int n_in,
                              void* d_out, int out_size, void* d_ws, size_t ws_size,
                              hipStream_t stream) {
    const float* X     = (const float*)d_in[0];
    const float* C     = (const float*)d_in[1];
    const float* alpha = (const float*)d_in[2];
    float* out = (float*)d_out;
    const int N = in_sizes[0] / D_DIM;   // 65536

    unsigned short* Cbws = (unsigned short*)d_ws;
    float* csq = (float*)((char*)d_ws + (size_t)K_CL * D_DIM * sizeof(unsigned short));

    prep_centers_kernel<<<K_CL, 64, 0, stream>>>(C, Cbws, csq);
    dec_main_kernel<<<N / BM, 512, 0, stream>>>(X, Cbws, csq, alpha, out);
}

// Round 5
// 119.686 us; speedup vs baseline: 1.0728x; 1.0728x over previous
//
#include <hip/hip_runtime.h>
#include <hip/hip_bf16.h>

#define D_DIM 768
#define K_CL  512
#define BM    64
#define BK    32
#define NSTEP 24          // 768 / 32

using f32x4 = __attribute__((ext_vector_type(4))) float;
using s16x8 = __attribute__((ext_vector_type(8))) short;
using u16x8 = __attribute__((ext_vector_type(8))) unsigned short;
using u16x4 = __attribute__((ext_vector_type(4))) unsigned short;

static __device__ __forceinline__ unsigned short f2bf(float f) {
    __hip_bfloat16 h = __float2bfloat16(f);   // RTN
    unsigned short u;
    __builtin_memcpy(&u, &h, 2);
    return u;
}

// Prepass: C[512][768] fp32 -> bf16 workspace in MFMA-fragment order:
// granule (16B = 8 bf16)  g = t*2048 + (r>>6)*256 + ((r>>4)&3)*64 + s*16 + (r&15)
// holds C[r][t*32 + s*8 .. +8).  In the main kernel, wave wn / lane (fg*16+fr)
// loads frag (t,nf) at granule  t*2048 + wn*256 + nf*64 + lane  -> lane-linear,
// perfectly coalesced 1 KB per instruction.  Also c_sq[512].
__global__ void prep_centers_kernel(const float* __restrict__ C,
                                    unsigned short* __restrict__ Cbws,
                                    float* __restrict__ csq) {
    const int r = blockIdx.x;          // 0..511
    const int l = threadIdx.x;         // 0..63
    const float* src = C + (size_t)r * D_DIM;
    float sq = 0.f;
#pragma unroll
    for (int jj = 0; jj < 2; ++jj) {
        const int j = l + jj * 64;     // 0..127, only 0..95 valid
        if (j < 96) {
            const int t = j >> 2, s = j & 3;
            const int k0 = t * 32 + s * 8;
            f32x4 v0 = *reinterpret_cast<const f32x4*>(src + k0);
            f32x4 v1 = *reinterpret_cast<const f32x4*>(src + k0 + 4);
            u16x8 b;
            b[0] = f2bf(v0[0]); b[1] = f2bf(v0[1]); b[2] = f2bf(v0[2]); b[3] = f2bf(v0[3]);
            b[4] = f2bf(v1[0]); b[5] = f2bf(v1[1]); b[6] = f2bf(v1[2]); b[7] = f2bf(v1[3]);
            sq += v0[0]*v0[0] + v0[1]*v0[1] + v0[2]*v0[2] + v0[3]*v0[3]
                + v1[0]*v1[0] + v1[1]*v1[1] + v1[2]*v1[2] + v1[3]*v1[3];
            const int g = t * 2048 + (r >> 6) * 256 + ((r >> 4) & 3) * 64
                        + s * 16 + (r & 15);
            *reinterpret_cast<u16x8*>(Cbws + (size_t)g * 8) = b;
        }
    }
#pragma unroll
    for (int m = 1; m < 64; m <<= 1) sq += __shfl_xor(sq, m, 64);
    if (l == 0) csq[r] = sq;
}

// Main: 64 rows x 512 clusters per block, 8 waves, wave tile 64x64.
// A: reg->LDS double-buffer (shared by all 8 waves).  B: NO LDS — each wave
// loads its private fragments straight from the fragment-ordered workspace
// (L2-resident), reloading the same regs right after last MFMA use.
__global__ __launch_bounds__(512, 4) void dec_main_kernel(
    const float* __restrict__ X,
    const unsigned short* __restrict__ Cbws,
    const float* __restrict__ csq,
    const float* __restrict__ alpha_ptr,
    float* __restrict__ out)
{
    __shared__ unsigned short Al[2][BM * BK];      // 2 * 4 KB
    __shared__ float part[8][BM];                  // 2 KB
    __shared__ float xsql[BM];
    __shared__ float invl[BM];

    const int tid  = threadIdx.x;      // 0..511
    const int lane = tid & 63;
    const int wn   = tid >> 6;         // 0..7
    const int m0   = blockIdx.x * BM;

    // A staging: 8 threads per row, float4 each (verified swizzle, 0 conflicts)
    const int arow  = tid >> 3;
    const int acol8 = tid & 7;
    const float* aptr = X + (size_t)(m0 + arow) * D_DIM + acol8 * 4;
    const int awbyte = arow * 64
                     + ((((acol8 >> 1) ^ ((arow >> 1) & 3))) << 4)
                     + (acol8 & 1) * 8;

    // A fragment read base: aoff(mf) = abase + mf*1024  (XOR term mf-invariant)
    const int fr = lane & 15;
    const int fg = lane >> 4;
    const int abase = fr * 64 + ((fg ^ ((fr >> 1) & 3)) << 4);

    // B fragment pointer (ushort units): frag(t,nf) at +((t*2048+nf*64)*8)
    const unsigned short* bptr = Cbws + (size_t)(wn * 256 + lane) * 8;

    f32x4 acc[4][4] = {};
    s16x8 bA[4];
    float sqp = 0.f;

    // ---- prologue ----
    f32x4 areg = *reinterpret_cast<const f32x4*>(aptr);          // A tile 0
#pragma unroll
    for (int nf = 0; nf < 4; ++nf)
        bA[nf] = *reinterpret_cast<const s16x8*>(bptr + nf * 512); // B frags(0)
    {   // stage A(0)
        u16x4 ab;
        ab[0] = f2bf(areg[0]); ab[1] = f2bf(areg[1]);
        ab[2] = f2bf(areg[2]); ab[3] = f2bf(areg[3]);
        sqp += areg[0]*areg[0] + areg[1]*areg[1] + areg[2]*areg[2] + areg[3]*areg[3];
        *reinterpret_cast<u16x4*>((char*)&Al[0][0] + awbyte) = ab;
    }
    areg = *reinterpret_cast<const f32x4*>(aptr + BK);           // A tile 1
    asm volatile("s_waitcnt lgkmcnt(0)" ::: "memory");
    __builtin_amdgcn_sched_barrier(0);
    __builtin_amdgcn_s_barrier();

    for (int t = 0; t < NSTEP; ++t) {
        // compute(t): A frags from LDS, B frags already in regs
        {
            const char* ab = (const char*)&Al[t & 1][0] + abase;
            s16x8 afr[4];
#pragma unroll
            for (int mf = 0; mf < 4; ++mf)
                afr[mf] = *reinterpret_cast<const s16x8*>(ab + mf * 1024);
            __builtin_amdgcn_s_setprio(1);
#pragma unroll
            for (int nf = 0; nf < 4; ++nf) {
#pragma unroll
                for (int mf = 0; mf < 4; ++mf)
                    acc[mf][nf] = __builtin_amdgcn_mfma_f32_16x16x32_bf16(
                        afr[mf], bA[nf], acc[mf][nf], 0, 0, 0);
            }
            __builtin_amdgcn_s_setprio(0);
        }
        if (t + 1 < NSTEP) {
            // reload B frags(t+1) into same regs (full step of slack to land)
            const unsigned short* bp = bptr + (size_t)(t + 1) * 16384;
#pragma unroll
            for (int nf = 0; nf < 4; ++nf)
                bA[nf] = *reinterpret_cast<const s16x8*>(bp + nf * 512);
            // stage A(t+1), prefetch A(t+2)
            u16x4 ab;
            ab[0] = f2bf(areg[0]); ab[1] = f2bf(areg[1]);
            ab[2] = f2bf(areg[2]); ab[3] = f2bf(areg[3]);
            sqp += areg[0]*areg[0] + areg[1]*areg[1] + areg[2]*areg[2] + areg[3]*areg[3];
            *reinterpret_cast<u16x4*>((char*)&Al[(t + 1) & 1][0] + awbyte) = ab;
            if (t + 2 < NSTEP)
                areg = *reinterpret_cast<const f32x4*>(aptr + (t + 2) * BK);
            asm volatile("s_waitcnt lgkmcnt(0)" ::: "memory");  // A writes visible
            __builtin_amdgcn_sched_barrier(0);
            __builtin_amdgcn_s_barrier();                        // B/a loads stay in flight
        }
    }

    // ---- ||x||^2 per row ----
    sqp += __shfl_xor(sqp, 1, 64);
    sqp += __shfl_xor(sqp, 2, 64);
    sqp += __shfl_xor(sqp, 4, 64);
    if ((tid & 7) == 0) xsql[arow] = sqp;
    __syncthreads();

    const float alpha     = alpha_ptr[0];
    const float inv_alpha = 1.0f / alpha;
    const float power     = 0.5f * (alpha + 1.0f);
    const bool  p1        = (power == 1.0f);

    float csqr[4];
#pragma unroll
    for (int nf = 0; nf < 4; ++nf)
        csqr[nf] = csq[wn * 64 + nf * 16 + fr];

#pragma unroll
    for (int mf = 0; mf < 4; ++mf) {
#pragma unroll
        for (int j = 0; j < 4; ++j) {
            const int rloc = mf * 16 + fg * 4 + j;
            const float xs = xsql[rloc];
            float rp = 0.f;
#pragma unroll
            for (int nf = 0; nf < 4; ++nf) {
                float d2 = xs + csqr[nf] - 2.0f * acc[mf][nf][j];
                d2 = fmaxf(d2, 0.0f);
                const float base = 1.0f + d2 * inv_alpha;
                const float nm = p1 ? (1.0f / base)
                                    : exp2f(-power * log2f(base));
                acc[mf][nf][j] = nm;
                rp += nm;
            }
#pragma unroll
            for (int m = 1; m < 16; m <<= 1) rp += __shfl_xor(rp, m, 64);
            if (fr == 0) part[wn][rloc] = rp;
        }
    }
    __syncthreads();
    if (tid < BM) {
        float s = 0.f;
#pragma unroll
        for (int w = 0; w < 8; ++w) s += part[w][tid];
        invl[tid] = 1.0f / s;
    }
    __syncthreads();

#pragma unroll
    for (int mf = 0; mf < 4; ++mf) {
#pragma unroll
        for (int j = 0; j < 4; ++j) {
            const int rloc = mf * 16 + fg * 4 + j;
            const float iv = invl[rloc];
            float* orow = out + (size_t)(m0 + rloc) * K_CL + wn * 64 + fr;
#pragma unroll
            for (int nf = 0; nf < 4; ++nf)
                orow[nf * 16] = acc[mf][nf][j] * iv;
        }
    }
}

extern "C" void kernel_launch(void* const* d_in, const int* in_sizes, int n_in,
                              void* d_out, int out_size, void* d_ws, size_t ws_size,
                              hipStream_t stream) {
    const float* X     = (const float*)d_in[0];
    const float* C     = (const float*)d_in[1];
    const float* alpha = (const float*)d_in[2];
    float* out = (float*)d_out;
    const int N = in_sizes[0] / D_DIM;   // 65536

    unsigned short* Cbws = (unsigned short*)d_ws;
    float* csq = (float*)((char*)d_ws + (size_t)K_CL * D_DIM * sizeof(unsigned short));

    prep_centers_kernel<<<K_CL, 64, 0, stream>>>(C, Cbws, csq);
    dec_main_kernel<<<N / BM, 512, 0, stream>>>(X, Cbws, csq, alpha, out);
}